// Round 2
// baseline (510.367 us; speedup 1.0000x reference)
//
#include <hip/hip_runtime.h>
#include <math.h>

// LearnableTD reverse scan: lambda_returns + sum_rewards.
// v3: two-dispatch structure.
//   Kernel A (1 tiny block): precompute lam[S] and gamma into d_ws ONCE
//     (bitwise-identical libm formula). Previously every one of 32768 blocks
//     recomputed 4 sigmoids/thread (~33M expf calls total) -> pure VALU waste
//     overlapping imperfectly with the HBM stream.
//   Kernel B (main): one block per batch row; 256 threads x 4 contiguous
//     timesteps; affine suffix scan:
//       sr_t = r_t                                + b_t * sr_{t+1}
//       lr_t = r_t + gamma*(1-d)*(1-lam)*v_{t+1}  + b_t * lr_{t+1}
//     per-thread compose -> wave shuffle suffix scan (no barriers) ->
//     one LDS exchange of 4 wave aggregates -> replay.

#define DF_C 0.99f
#define AL_C 0.95f

__global__ __launch_bounds__(256) void td_precompute_kernel(
    const float* __restrict__ raw_gamma, // (1,)
    const float* __restrict__ raw_lambd, // (S,)
    float* __restrict__ ws,              // [lam (S) | gamma (1)]
    int S)
{
    const int i0 = threadIdx.x * 4;
    if (threadIdx.x == 0) {
        const float rg = raw_gamma[0];
        const float sg = 1.0f / (1.0f + expf(-rg));
        ws[S] = DF_C + (1.0f - DF_C) * (2.0f * sg - 1.0f);
    }
#pragma unroll
    for (int j = 0; j < 4; ++j) {
        const int i = i0 + j;
        if (i < S) {
            const float x = raw_lambd[i];
            const float s = 1.0f / (1.0f + expf(-x));
            ws[i] = AL_C + (1.0f - AL_C) * (2.0f * s - 1.0f);
        }
    }
}

__global__ __launch_bounds__(256) void td_scan_kernel(
    const float* __restrict__ values,    // (B, S+1)
    const float* __restrict__ rewards,   // (B, S)
    const float* __restrict__ dones,     // (B, S)
    const float* __restrict__ ws,        // [lam (S) | gamma (1)] (L2-resident)
    float* __restrict__ out,             // [lambda_returns (B,S) | sum_rewards (B,S)]
    int B, int S)
{
    const int b    = blockIdx.x;
    const int tid  = threadIdx.x;
    const int lane = tid & 63;
    const int wv   = tid >> 6;          // wave id, 0..3
    const int t0   = tid * 4;

    const float gamma = ws[S];          // uniform scalar, L2-resident

    // Payload loads: coalesced float4 for rewards/dones/lam (16B aligned:
    // t0 % 4 == 0, row base b*S is a multiple of 4 elements).
    const size_t rbase = (size_t)b * S + t0;
    const float4 r4 = *reinterpret_cast<const float4*>(rewards + rbase);
    const float4 d4 = *reinterpret_cast<const float4*>(dones   + rbase);
    const float4 l4 = *reinterpret_cast<const float4*>(ws + t0);
    float r[4]   = {r4.x, r4.y, r4.z, r4.w};
    float d[4]   = {d4.x, d4.y, d4.z, d4.w};
    float lam[4] = {l4.x, l4.y, l4.z, l4.w};

    // values row is offset by +1 elem (row length S+1 = odd -> no 16B
    // alignment possible); __builtin_memcpy lets the compiler pick the widest
    // legal loads at 4B alignment. Lines are fully consumed via L1 either way.
    const float* vrow = values + (size_t)b * (S + 1);
    float v[4];
    __builtin_memcpy(v, vrow + t0 + 1, 16);      // v_next at t0..t0+3
    const float v_last = vrow[S];                // uniform per block

    // Local composition F_tid = f_{t0} o f_{t0+1} o f_{t0+2} o f_{t0+3}
    // (G o f)(x) = A_G + B_G*a_f + B_G*b_f*x
    float Al = 0.0f, As = 0.0f, Bp = 1.0f;
#pragma unroll
    for (int j = 0; j < 4; ++j) {
        const float g  = gamma * (1.0f - d[j]);
        const float bt = g * lam[j];
        const float at = r[j] + g * (1.0f - lam[j]) * v[j];
        Al = Al + Bp * at;
        As = As + Bp * r[j];
        Bp = Bp * bt;
    }

    // Wave-level inclusive SUFFIX scan (Kogge-Stone over 64 lanes, no barriers)
#pragma unroll
    for (int off = 1; off < 64; off <<= 1) {
        const float al  = __shfl_down(Al, off);
        const float as_ = __shfl_down(As, off);
        const float bb  = __shfl_down(Bp, off);
        if (lane + off < 64) {
            Al = Al + Bp * al;   // self o neighbor
            As = As + Bp * as_;
            Bp = Bp * bb;
        }
    }

    // Exclusive suffix within the wave = inclusive suffix of lane+1.
    float eAl = __shfl_down(Al, 1);
    float eAs = __shfl_down(As, 1);
    float eB  = __shfl_down(Bp, 1);
    if (lane == 63) { eAl = 0.0f; eAs = 0.0f; eB = 1.0f; }

    // Cross-wave: lane 0 of each wave holds the whole-wave composition W_w.
    __shared__ float wA_l[4], wA_s[4], wB_[4];
    if (lane == 0) { wA_l[wv] = Al; wA_s[wv] = As; wB_[wv] = Bp; }
    __syncthreads();

    // Compose with later waves: E = W_{wv+1} o ... o W_3 (wave-uniform loop).
    for (int w2 = wv + 1; w2 < 4; ++w2) {
        eAl = eAl + eB * wA_l[w2];
        eAs = eAs + eB * wA_s[w2];
        eB  = eB  * wB_[w2];
    }

    // Apply to init: lr_init = values[b][S], sr_init = 0
    float lr = eAl + eB * v_last;
    float sr = eAs;

    // Local replay right-to-left, producing the 4 outputs
    float out_lr[4], out_sr[4];
#pragma unroll
    for (int j = 3; j >= 0; --j) {
        const float g  = gamma * (1.0f - d[j]);
        const float bt = g * lam[j];
        sr = r[j] + bt * sr;
        lr = r[j] + g * (1.0f - lam[j]) * v[j] + bt * lr;
        out_lr[j] = lr;
        out_sr[j] = sr;
    }

    *reinterpret_cast<float4*>(out + rbase) =
        make_float4(out_lr[0], out_lr[1], out_lr[2], out_lr[3]);
    *reinterpret_cast<float4*>(out + (size_t)B * S + rbase) =
        make_float4(out_sr[0], out_sr[1], out_sr[2], out_sr[3]);
}

extern "C" void kernel_launch(void* const* d_in, const int* in_sizes, int n_in,
                              void* d_out, int out_size, void* d_ws, size_t ws_size,
                              hipStream_t stream) {
    const float* values    = (const float*)d_in[0];
    const float* rewards   = (const float*)d_in[1];
    const float* dones     = (const float*)d_in[2];
    const float* raw_gamma = (const float*)d_in[3];
    const float* raw_lambd = (const float*)d_in[4];
    float* out = (float*)d_out;
    float* ws  = (float*)d_ws;           // needs (S+1)*4 bytes

    const int S = in_sizes[4];       // raw_lambd has length S
    const int B = in_sizes[1] / S;   // rewards is B*S

    // Kernel A: precompute lam[S] + gamma once (tiny, one block).
    td_precompute_kernel<<<dim3(1), dim3((S + 3) / 4), 0, stream>>>(
        raw_gamma, raw_lambd, ws, S);

    // Kernel B: the scan. One block per row; 256 threads x 4 timesteps.
    td_scan_kernel<<<dim3(B), dim3(S / 4), 0, stream>>>(
        values, rewards, dones, ws, out, B, S);
}